// Round 2
// baseline (491.637 us; speedup 1.0000x reference)
//
#include <hip/hip_runtime.h>
#include <hip/hip_bf16.h>
#include <math.h>

#define NROWS 131072   // B*T = 32*4096
#define KC    512      // codebook size
#define DD    64       // embedding dim
#define NELEM (NROWS * DD)

#define OUT_IDX_OFF  NELEM
#define OUT_LOSS_OFF (NELEM + NROWS)

#define MARGIN 3e-5f

// d_ws byte offsets
#define WSO_CNT   0                        // int   flagged-row count
#define WSO_DONE  4                        // int   refine blocks-done count
#define WSO_LOSS  8                        // float loss accumulator
#define WSO_WNORM 64                       // float wnorm_np[512]
#define WSO_BH    4096                     // bf16 frags W-hi: 32 tiles x 2 kh x 64 lanes x 8 = 64 KB
#define WSO_BL    (WSO_BH + 65536)         // bf16 frags W-lo: 64 KB
#define WSO_LIST  (WSO_BL + 65536)         // int flagList[NROWS]

typedef __attribute__((ext_vector_type(8))) short short8;
typedef __attribute__((ext_vector_type(4))) float f32x4;

// ---------------------------------------------------------------------------
// bf16 helpers (RNE via __float2bfloat16)
// ---------------------------------------------------------------------------
__device__ __forceinline__ short f2bf_bits(float f) {
  __hip_bfloat16 h = __float2bfloat16(f);
  short s; __builtin_memcpy(&s, &h, 2); return s;
}
__device__ __forceinline__ float bfbits2f(short s) {
  __hip_bfloat16 h; __builtin_memcpy(&h, &s, 2);
  return __bfloat162float(h);
}
// split 8 consecutive f32 into bf16 hi + bf16 lo(residual)
__device__ __forceinline__ void cvt8(const float* __restrict__ p, short8& hi, short8& lo) {
#pragma unroll
  for (int j = 0; j < 8; j++) {
    float f = p[j];
    short hb = f2bf_bits(f);
    float r = f - bfbits2f(hb);
    hi[j] = hb;
    lo[j] = f2bf_bits(r);
  }
}

// ---------------------------------------------------------------------------
// numpy's pairwise sum of squares for 64 contiguous f32 (8-accumulator tree).
// contract(off) REQUIRED (hipcc default -ffp-contract=fast would fuse).
// ---------------------------------------------------------------------------
__device__ __forceinline__ float np_sumsq64(const float* __restrict__ p) {
#pragma clang fp contract(off)
  float r0 = p[0] * p[0], r1 = p[1] * p[1], r2 = p[2] * p[2], r3 = p[3] * p[3];
  float r4 = p[4] * p[4], r5 = p[5] * p[5], r6 = p[6] * p[6], r7 = p[7] * p[7];
  for (int i = 8; i < 64; i += 8) {
    r0 = r0 + p[i + 0] * p[i + 0];
    r1 = r1 + p[i + 1] * p[i + 1];
    r2 = r2 + p[i + 2] * p[i + 2];
    r3 = r3 + p[i + 3] * p[i + 3];
    r4 = r4 + p[i + 4] * p[i + 4];
    r5 = r5 + p[i + 5] * p[i + 5];
    r6 = r6 + p[i + 6] * p[i + 6];
    r7 = r7 + p[i + 7] * p[i + 7];
  }
  return ((r0 + r1) + (r2 + r3)) + ((r4 + r5) + (r6 + r7));
}

// ---------------------------------------------------------------------------
// Kernel 0: prep. (a) W -> MFMA-B-fragment-major bf16 hi/lo arrays.
// B[k=d][n=cw] fragment for 16x16x32: lane L holds B[(L>>4)*8+j][L&15], j=0..7.
// Element (tile t, khalf h, lane L, j) = W[cw = t*16+(L&15)][d = 32h+(L>>4)*8+j].
// (b) wnorm_np[k] = numpy-exact sum(W[k]^2).  (c) zero ws scalars.
// ---------------------------------------------------------------------------
__global__ void k_prep(const float* __restrict__ W, short8* __restrict__ Bh,
                       short8* __restrict__ Bl, float* __restrict__ wnorm,
                       int* __restrict__ flagCnt, int* __restrict__ doneCnt,
                       float* __restrict__ lossSum) {
  int gtid = blockIdx.x * blockDim.x + threadIdx.x;  // 0..4095
  if (gtid == 0) { *flagCnt = 0; *doneCnt = 0; *lossSum = 0.0f; }
  int t = gtid >> 7, rem = gtid & 127;
  int h = rem >> 6, L = rem & 63;
  int cw = (t << 4) + (L & 15);
  int dbase = (h << 5) + ((L >> 4) << 3);
  short8 hi, lo;
  cvt8(W + (cw << 6) + dbase, hi, lo);
  Bh[gtid] = hi;  // gtid == ((t*2+h)*64 + L)
  Bl[gtid] = lo;
  if (gtid < KC) wnorm[gtid] = np_sumsq64(W + (gtid << 6));
}

// ---------------------------------------------------------------------------
// Kernel 1: fused MFMA screen + argmin + epilogue.
// GEOMETRY (round-2): block = 64 rows, 4 waves SPLIT THE K DIMENSION
// (wave w owns codeword tiles w*8..w*8+7). Rationale vs round-1 failure:
// splitting rows doubled per-wave B-traffic and halved MFMA ILP; splitting K
// shrinks per-wave B-traffic 4x while keeping MT=4 (4 indep acc chains).
// Grid 2048 blocks -> 8192 waves (3-4x round-0 occupancy).
// A fragments are built ONCE per block into LDS (coop cvt), each wave
// ds_reads the full 64-row A set. Per-wave argmin over its 128 codewords,
// then LDS cross-wave merge (ascending-wave order + strict < keeps lowest k).
// score_k = wnorm_np[k] - 2*(zh.wh + zl.wh + zh.wl); err ~3e-6 << MARGIN.
// ---------------------------------------------------------------------------
#define MT 4
#define ROWS_PER_BLOCK 64
#define TPW 8   // codeword tiles per wave

__global__ __launch_bounds__(256, 6) void k_screen(
    const float* __restrict__ z, const float* __restrict__ W,
    const short8* __restrict__ Bh, const short8* __restrict__ Bl,
    const float* __restrict__ wnorm, float* __restrict__ out,
    int* __restrict__ flagList, int* __restrict__ flagCnt,
    float* __restrict__ lossSum) {
  const int tid = threadIdx.x;
  const int lane = tid & 63;
  const int wave = tid >> 6;
  const int rowBase = blockIdx.x * ROWS_PER_BLOCK;
  const int m = lane & 15, quad = lane >> 4;

  __shared__ short8 sAh[MT * 2][64];   // 8 KB: A-frag hi, [(mt*2+h)][lane]
  __shared__ short8 sAl[MT * 2][64];   // 8 KB: A-frag lo
  __shared__ float sb1[4][64], sb2[4][64];  // per-wave argmin results
  __shared__ int   sbi[4][64];
  __shared__ float lw[4];

  // ---- cooperative A staging: thread handles 16 consecutive cols of 1 row --
  {
    const int row = tid >> 2;                 // 0..63
    const int colbase = (tid & 3) << 4;       // 0,16,32,48
    const int mt = row >> 4, mm = row & 15;
    const int h = colbase >> 5;               // 0 or 1 (never crosses)
    const int q0 = (colbase >> 3) & 3;
    const float* zp = z + (size_t)(rowBase + row) * DD + colbase;
    short8 hi0, lo0, hi1, lo1;
    cvt8(zp, hi0, lo0);
    cvt8(zp + 8, hi1, lo1);
    const int f = mt * 2 + h;
    sAh[f][(q0 << 4) + mm] = hi0;       sAl[f][(q0 << 4) + mm] = lo0;
    sAh[f][((q0 + 1) << 4) + mm] = hi1; sAl[f][((q0 + 1) << 4) + mm] = lo1;
  }
  __syncthreads();

  // ---- A fragments from LDS (full 64-row set per wave) ----
  short8 Ah[MT][2], Al[MT][2];
#pragma unroll
  for (int mt = 0; mt < MT; mt++)
#pragma unroll
    for (int h = 0; h < 2; h++) {
      Ah[mt][h] = sAh[mt * 2 + h][lane];
      Al[mt][h] = sAl[mt * 2 + h][lane];
    }

  float b1[MT][4], b2[MT][4];
  int bi[MT][4];
#pragma unroll
  for (int mt = 0; mt < MT; mt++)
#pragma unroll
    for (int r = 0; r < 4; r++) { b1[mt][r] = 1e30f; b2[mt][r] = 1e30f; bi[mt][r] = 0; }

  // ---- this wave's 8 codeword tiles, register prefetch 1 ahead ----
  const int tbase = wave * TPW;
  short8 cBh[2], cBl[2];
#pragma unroll
  for (int h = 0; h < 2; h++) {
    cBh[h] = Bh[(((tbase << 1) + h) << 6) + lane];
    cBl[h] = Bl[(((tbase << 1) + h) << 6) + lane];
  }
  float cwn = wnorm[(tbase << 4) + m];

#pragma unroll
  for (int tl = 0; tl < TPW; tl++) {
    const int t = tbase + tl;
    const int tn = tbase + ((tl + 1) & (TPW - 1));  // wrap harmless
    short8 nBh[2], nBl[2];
#pragma unroll
    for (int h = 0; h < 2; h++) {
      nBh[h] = Bh[(((tn << 1) + h) << 6) + lane];
      nBl[h] = Bl[(((tn << 1) + h) << 6) + lane];
    }
    float nwn = wnorm[(tn << 4) + m];

    f32x4 acc[MT] = {{0.f, 0.f, 0.f, 0.f}, {0.f, 0.f, 0.f, 0.f},
                     {0.f, 0.f, 0.f, 0.f}, {0.f, 0.f, 0.f, 0.f}};
#pragma unroll
    for (int h = 0; h < 2; h++) {
#pragma unroll
      for (int mt = 0; mt < MT; mt++)
        acc[mt] = __builtin_amdgcn_mfma_f32_16x16x32_bf16(Ah[mt][h], cBh[h], acc[mt], 0, 0, 0);
#pragma unroll
      for (int mt = 0; mt < MT; mt++)
        acc[mt] = __builtin_amdgcn_mfma_f32_16x16x32_bf16(Al[mt][h], cBh[h], acc[mt], 0, 0, 0);
#pragma unroll
      for (int mt = 0; mt < MT; mt++)
        acc[mt] = __builtin_amdgcn_mfma_f32_16x16x32_bf16(Ah[mt][h], cBl[h], acc[mt], 0, 0, 0);
    }

    const int colv = (t << 4) + m;
#pragma unroll
    for (int mt = 0; mt < MT; mt++)
#pragma unroll
      for (int r = 0; r < 4; r++) {
        float s = fmaf(-2.0f, acc[mt][r], cwn);
        if (s < b1[mt][r]) { b2[mt][r] = b1[mt][r]; b1[mt][r] = s; bi[mt][r] = colv; }
        else b2[mt][r] = fminf(b2[mt][r], s);
      }

    cBh[0] = nBh[0]; cBh[1] = nBh[1];
    cBl[0] = nBl[0]; cBl[1] = nBl[1];
    cwn = nwn;
  }

  // ---- in-wave butterfly over the 16 col-lanes (within quad group) ----
#pragma unroll
  for (int off = 1; off < 16; off <<= 1) {
#pragma unroll
    for (int mt = 0; mt < MT; mt++)
#pragma unroll
      for (int r = 0; r < 4; r++) {
        float o1 = __shfl_xor(b1[mt][r], off, 64);
        float o2 = __shfl_xor(b2[mt][r], off, 64);
        int oi = __shfl_xor(bi[mt][r], off, 64);
        if (o1 < b1[mt][r] || (o1 == b1[mt][r] && oi < bi[mt][r])) {
          b2[mt][r] = fminf(b1[mt][r], o2);
          b1[mt][r] = o1; bi[mt][r] = oi;
        } else {
          b2[mt][r] = fminf(b2[mt][r], o1);
        }
      }
  }

  // ---- publish per-wave results (uniform in each quad group) ----
  if (m == 0) {  // 4 lanes per wave, one per quad
#pragma unroll
    for (int mt = 0; mt < MT; mt++)
#pragma unroll
      for (int r = 0; r < 4; r++) {
        const int rl = (mt << 4) + (quad << 2) + r;
        sb1[wave][rl] = b1[mt][r];
        sb2[wave][rl] = b2[mt][r];
        sbi[wave][rl] = bi[mt][r];
      }
  }
  __syncthreads();

  // ---- cross-wave merge; wave w finalizes rows [w*16, w*16+16) ----
  // Ascending wave order covers ascending k ranges -> strict < keeps lowest k.
  const int rl = (wave << 4) + m;  // all 4 quads compute redundantly
  float B1 = sb1[0][rl], B2 = sb2[0][rl];
  int KI = sbi[0][rl];
#pragma unroll
  for (int w2 = 1; w2 < 4; w2++) {
    float o1 = sb1[w2][rl], o2 = sb2[w2][rl];
    int oi = sbi[w2][rl];
    if (o1 < B1) { B2 = fminf(B1, o2); B1 = o1; KI = oi; }
    else B2 = fminf(B2, o1);  // o2 >= o1 so min(B2,o1) suffices
  }
  if (lane < 16) {
    const int row = rowBase + rl;
    out[OUT_IDX_OFF + row] = (float)KI;
    if (B2 - B1 < MARGIN) {
      int slot = atomicAdd(flagCnt, 1);
      flagList[slot] = row;
    }
  }

  // ---- epilogue: wave's 16 rows, 16 lanes x f32x4 per row, 4 rows/iter ----
  float lossAcc = 0.f;
#pragma unroll
  for (int sub = 0; sub < 4; sub++) {
    const int ro = (sub << 2) + quad;                 // row offset 0..15
    const int row = rowBase + (wave << 4) + ro;
    const int kr = __shfl(KI, ro, 64);                // lane ro holds row ro's KI
    f32x4 zv = *(const f32x4*)(z + (size_t)row * DD + (m << 2));
    f32x4 wv = *(const f32x4*)(W + (kr << 6) + (m << 2));
    f32x4 ov;
#pragma unroll
    for (int j = 0; j < 4; j++) {
      float tt = wv[j] - zv[j];
      ov[j] = zv[j] + tt;  // matches reference z + (z_q - z)
      float dl = zv[j] - ov[j];
      lossAcc = fmaf(dl, dl, lossAcc);
    }
    *(f32x4*)(out + (size_t)row * DD + (m << 2)) = ov;
  }

  // ---- block-level loss reduction (1 atomic per block, not per wave) ----
#pragma unroll
  for (int off = 1; off < 64; off <<= 1) lossAcc += __shfl_xor(lossAcc, off, 64);
  if (lane == 0) lw[wave] = lossAcc;
  __syncthreads();
  if (tid == 0) atomicAdd(lossSum, (lw[0] + lw[1]) + (lw[2] + lw[3]));
}

// ---------------------------------------------------------------------------
// Kernel 2: numpy-f32 replication for flagged rows + patch out/loss.
// dist_np = fl32( fl32(A + wnp[k]) - fl32(2*C) ), C = f64 dot rounded once.
// Tail: last-block-done pattern finalizes the loss.
// ---------------------------------------------------------------------------
__global__ void k_refine(const float* __restrict__ z, const float* __restrict__ W,
                         const float* __restrict__ wnp, float* __restrict__ out,
                         const int* __restrict__ flagList,
                         const int* __restrict__ flagCnt,
                         float* __restrict__ lossSum, int* __restrict__ doneCnt) {
  int nflag = *flagCnt;
  int lane = threadIdx.x & 63;
  int wave = (blockIdx.x * blockDim.x + threadIdx.x) >> 6;
  int nWaves = (gridDim.x * blockDim.x) >> 6;

  for (int f = wave; f < nflag; f += nWaves) {
    int row = flagList[f];
    const float* zr = z + (size_t)row * DD;
    float A = np_sumsq64(zr);

    float best = 1e30f;
    int bk = 0x7fffffff;
#pragma unroll
    for (int j = 0; j < KC / 64; j++) {
      int k = lane + (j << 6);
      const float* wk = W + (k << 6);
      double cd = 0.0;
      for (int d = 0; d < DD; d++) cd = fma((double)zr[d], (double)wk[d], cd);
      float twoC = (float)(2.0 * cd);
      float dist;
      {
#pragma clang fp contract(off)
        float t1 = A + wnp[k];
        dist = t1 - twoC;
      }
      if (dist < best || (dist == best && k < bk)) { best = dist; bk = k; }
    }
#pragma unroll
    for (int off = 1; off < 64; off <<= 1) {
      float ov = __shfl_xor(best, off, 64);
      int ok = __shfl_xor(bk, off, 64);
      if (ov < best || (ov == best && ok < bk)) { best = ov; bk = ok; }
    }

    int kold = (int)out[OUT_IDX_OFF + row];
    if (bk != kold) {
      float zv = zr[lane];
      float wN = W[(bk << 6) + lane];
      float oOld = out[(size_t)row * DD + lane];
      float tN = wN - zv;
      float oN = zv + tN;
      out[(size_t)row * DD + lane] = oN;
      float dN = zv - oN, dO = zv - oOld;
      float delta = dN * dN - dO * dO;
#pragma unroll
      for (int off = 1; off < 64; off <<= 1) delta += __shfl_xor(delta, off, 64);
      if (lane == 0) {
        atomicAdd(lossSum, delta);
        out[OUT_IDX_OFF + row] = (float)bk;
      }
    }
  }

  // ---- finalize: last block to arrive writes the loss scalar ----
  __syncthreads();
  if (threadIdx.x == 0) {
    __threadfence();
    int d = atomicAdd(doneCnt, 1);
    if (d == (int)gridDim.x - 1) {
      float s = atomicAdd(lossSum, 0.0f);  // atomic read sees all prior adds
      out[OUT_LOSS_OFF] = 0.25f * s / (float)NELEM;
    }
  }
}

extern "C" void kernel_launch(void* const* d_in, const int* in_sizes, int n_in,
                              void* d_out, int out_size, void* d_ws, size_t ws_size,
                              hipStream_t stream) {
  const float* z = (const float*)d_in[0];
  const float* W = (const float*)d_in[1];
  float* out = (float*)d_out;
  char* ws = (char*)d_ws;

  int* flagCnt = (int*)(ws + WSO_CNT);
  int* doneCnt = (int*)(ws + WSO_DONE);
  float* lossSum = (float*)(ws + WSO_LOSS);
  float* wnorm = (float*)(ws + WSO_WNORM);
  short8* Bh = (short8*)(ws + WSO_BH);
  short8* Bl = (short8*)(ws + WSO_BL);
  int* flagList = (int*)(ws + WSO_LIST);

  k_prep<<<16, 256, 0, stream>>>(W, Bh, Bl, wnorm, flagCnt, doneCnt, lossSum);
  k_screen<<<NROWS / ROWS_PER_BLOCK, 256, 0, stream>>>(z, W, Bh, Bl, wnorm, out,
                                                       flagList, flagCnt, lossSum);
  k_refine<<<256, 256, 0, stream>>>(z, W, wnorm, out, flagList, flagCnt,
                                    lossSum, doneCnt);
}

// Round 3
// 236.258 us; speedup vs baseline: 2.0809x; 2.0809x over previous
//
#include <hip/hip_runtime.h>
#include <hip/hip_bf16.h>
#include <math.h>

#define NROWS 131072   // B*T = 32*4096
#define KC    512      // codebook size
#define DD    64       // embedding dim
#define NELEM (NROWS * DD)

#define OUT_IDX_OFF  NELEM
#define OUT_LOSS_OFF (NELEM + NROWS)

#define MARGIN 3e-5f

// d_ws byte offsets
#define WSO_CNT   0                        // int   flagged-row count
#define WSO_DONE  4                        // int   refine blocks-done count
#define WSO_LOSS  8                        // float loss accumulator
#define WSO_WNORM 64                       // float wnorm_np[512]
#define WSO_BH    4096                     // bf16 frags W-hi: 32 tiles x 2 kh x 64 lanes x 8 = 64 KB
#define WSO_BL    (WSO_BH + 65536)         // bf16 frags W-lo: 64 KB
#define WSO_LIST  (WSO_BL + 65536)         // int flagList[NROWS]

typedef __attribute__((ext_vector_type(8))) short short8;
typedef __attribute__((ext_vector_type(4))) float f32x4;

// ---------------------------------------------------------------------------
// bf16 helpers (RNE via __float2bfloat16)
// ---------------------------------------------------------------------------
__device__ __forceinline__ short f2bf_bits(float f) {
  __hip_bfloat16 h = __float2bfloat16(f);
  short s; __builtin_memcpy(&s, &h, 2); return s;
}
__device__ __forceinline__ float bfbits2f(short s) {
  __hip_bfloat16 h; __builtin_memcpy(&h, &s, 2);
  return __bfloat162float(h);
}
// split 8 consecutive f32 into bf16 hi + bf16 lo(residual)
__device__ __forceinline__ void cvt8(const float* __restrict__ p, short8& hi, short8& lo) {
#pragma unroll
  for (int j = 0; j < 8; j++) {
    float f = p[j];
    short hb = f2bf_bits(f);
    float r = f - bfbits2f(hb);
    hi[j] = hb;
    lo[j] = f2bf_bits(r);
  }
}

// ---------------------------------------------------------------------------
// numpy's pairwise sum of squares for 64 contiguous f32 (8-accumulator tree).
// contract(off) REQUIRED (hipcc default -ffp-contract=fast would fuse).
// ---------------------------------------------------------------------------
__device__ __forceinline__ float np_sumsq64(const float* __restrict__ p) {
#pragma clang fp contract(off)
  float r0 = p[0] * p[0], r1 = p[1] * p[1], r2 = p[2] * p[2], r3 = p[3] * p[3];
  float r4 = p[4] * p[4], r5 = p[5] * p[5], r6 = p[6] * p[6], r7 = p[7] * p[7];
  for (int i = 8; i < 64; i += 8) {
    r0 = r0 + p[i + 0] * p[i + 0];
    r1 = r1 + p[i + 1] * p[i + 1];
    r2 = r2 + p[i + 2] * p[i + 2];
    r3 = r3 + p[i + 3] * p[i + 3];
    r4 = r4 + p[i + 4] * p[i + 4];
    r5 = r5 + p[i + 5] * p[i + 5];
    r6 = r6 + p[i + 6] * p[i + 6];
    r7 = r7 + p[i + 7] * p[i + 7];
  }
  return ((r0 + r1) + (r2 + r3)) + ((r4 + r5) + (r6 + r7));
}

// ---------------------------------------------------------------------------
// Kernel 0: prep. (a) W -> MFMA-B-fragment-major bf16 hi/lo arrays.
// B[k=d][n=cw] fragment for 16x16x32: lane L holds B[(L>>4)*8+j][L&15], j=0..7.
// Element (tile t, khalf h, lane L, j) = W[cw = t*16+(L&15)][d = 32h+(L>>4)*8+j].
// (b) wnorm_np[k] = numpy-exact sum(W[k]^2).  (c) zero ws scalars.
// ---------------------------------------------------------------------------
__global__ void k_prep(const float* __restrict__ W, short8* __restrict__ Bh,
                       short8* __restrict__ Bl, float* __restrict__ wnorm,
                       int* __restrict__ flagCnt, int* __restrict__ doneCnt,
                       float* __restrict__ lossSum) {
  int gtid = blockIdx.x * blockDim.x + threadIdx.x;  // 0..4095
  if (gtid == 0) { *flagCnt = 0; *doneCnt = 0; *lossSum = 0.0f; }
  int t = gtid >> 7, rem = gtid & 127;
  int h = rem >> 6, L = rem & 63;
  int cw = (t << 4) + (L & 15);
  int dbase = (h << 5) + ((L >> 4) << 3);
  short8 hi, lo;
  cvt8(W + (cw << 6) + dbase, hi, lo);
  Bh[gtid] = hi;  // gtid == ((t*2+h)*64 + L)
  Bl[gtid] = lo;
  if (gtid < KC) wnorm[gtid] = np_sumsq64(W + (gtid << 6));
}

// ---------------------------------------------------------------------------
// Kernel 1: fused MFMA screen + argmin + epilogue.
// GEOMETRY (round-3): block = 64 rows, 4 waves split the K dimension
// (wave w owns codeword tiles w*8..w*8+7), grid 2048 blocks -> 8192 waves.
// Round-2 post-mortem fixes baked in:
//   (a) NO min-waves launch_bounds clamp. (256,6) forced VGPR=40 -> the 16
//       short8 A-frags + argmin state spilled to scratch (FETCH 557MB /
//       WRITE 862MB of pure spill traffic). Default bounds -> ~84-110 VGPR,
//       no spill, still 4+ waves/SIMD.
//   (b) NO LDS A-staging. 32B-stride ds_reads were a 786K bank-conflict hit.
//       Each wave rebuilds A-frags from global (~256 VALU, once); waves 1-3
//       read the same 16KB of z -> L1 hits. Only the tiny 4B-stride argmin
//       merge arrays stay in LDS.
// score_k = wnorm_np[k] - 2*(zh.wh + zl.wh + zh.wl); err ~3e-6 << MARGIN.
// Cross-wave merge: ascending-wave order covers ascending k -> strict <
// keeps lowest index (argmin first-index semantics preserved).
// ---------------------------------------------------------------------------
#define MT 4
#define ROWS_PER_BLOCK 64
#define TPW 8   // codeword tiles per wave

__global__ __launch_bounds__(256) void k_screen(
    const float* __restrict__ z, const float* __restrict__ W,
    const short8* __restrict__ Bh, const short8* __restrict__ Bl,
    const float* __restrict__ wnorm, float* __restrict__ out,
    int* __restrict__ flagList, int* __restrict__ flagCnt,
    float* __restrict__ lossSum) {
  const int tid = threadIdx.x;
  const int lane = tid & 63;
  const int wave = tid >> 6;
  const int rowBase = blockIdx.x * ROWS_PER_BLOCK;
  const int m = lane & 15, quad = lane >> 4;

  __shared__ float sb1[4][64], sb2[4][64];  // per-wave argmin results (4B stride)
  __shared__ int   sbi[4][64];
  __shared__ float lw[4];

  // ---- A fragments: zh/zl for 4 M-tiles x 2 k-halves, built per-wave ----
  short8 Ah[MT][2], Al[MT][2];
#pragma unroll
  for (int mt = 0; mt < MT; mt++) {
    const float* zp = z + (size_t)(rowBase + (mt << 4) + m) * DD + (quad << 3);
#pragma unroll
    for (int h = 0; h < 2; h++) cvt8(zp + (h << 5), Ah[mt][h], Al[mt][h]);
  }

  float b1[MT][4], b2[MT][4];
  int bi[MT][4];
#pragma unroll
  for (int mt = 0; mt < MT; mt++)
#pragma unroll
    for (int r = 0; r < 4; r++) { b1[mt][r] = 1e30f; b2[mt][r] = 1e30f; bi[mt][r] = 0; }

  // ---- this wave's 8 codeword tiles, register prefetch 1 ahead ----
  const int tbase = wave * TPW;
  short8 cBh[2], cBl[2];
#pragma unroll
  for (int h = 0; h < 2; h++) {
    cBh[h] = Bh[(((tbase << 1) + h) << 6) + lane];
    cBl[h] = Bl[(((tbase << 1) + h) << 6) + lane];
  }
  float cwn = wnorm[(tbase << 4) + m];

#pragma unroll
  for (int tl = 0; tl < TPW; tl++) {
    const int t = tbase + tl;
    const int tn = tbase + ((tl + 1) & (TPW - 1));  // wrap harmless
    short8 nBh[2], nBl[2];
#pragma unroll
    for (int h = 0; h < 2; h++) {
      nBh[h] = Bh[(((tn << 1) + h) << 6) + lane];
      nBl[h] = Bl[(((tn << 1) + h) << 6) + lane];
    }
    float nwn = wnorm[(tn << 4) + m];

    f32x4 acc[MT] = {{0.f, 0.f, 0.f, 0.f}, {0.f, 0.f, 0.f, 0.f},
                     {0.f, 0.f, 0.f, 0.f}, {0.f, 0.f, 0.f, 0.f}};
#pragma unroll
    for (int h = 0; h < 2; h++) {
#pragma unroll
      for (int mt = 0; mt < MT; mt++)
        acc[mt] = __builtin_amdgcn_mfma_f32_16x16x32_bf16(Ah[mt][h], cBh[h], acc[mt], 0, 0, 0);
#pragma unroll
      for (int mt = 0; mt < MT; mt++)
        acc[mt] = __builtin_amdgcn_mfma_f32_16x16x32_bf16(Al[mt][h], cBh[h], acc[mt], 0, 0, 0);
#pragma unroll
      for (int mt = 0; mt < MT; mt++)
        acc[mt] = __builtin_amdgcn_mfma_f32_16x16x32_bf16(Ah[mt][h], cBl[h], acc[mt], 0, 0, 0);
    }

    const int colv = (t << 4) + m;
#pragma unroll
    for (int mt = 0; mt < MT; mt++)
#pragma unroll
      for (int r = 0; r < 4; r++) {
        float s = fmaf(-2.0f, acc[mt][r], cwn);
        if (s < b1[mt][r]) { b2[mt][r] = b1[mt][r]; b1[mt][r] = s; bi[mt][r] = colv; }
        else b2[mt][r] = fminf(b2[mt][r], s);
      }

    cBh[0] = nBh[0]; cBh[1] = nBh[1];
    cBl[0] = nBl[0]; cBl[1] = nBl[1];
    cwn = nwn;
  }

  // ---- in-wave butterfly over the 16 col-lanes (within quad group) ----
#pragma unroll
  for (int off = 1; off < 16; off <<= 1) {
#pragma unroll
    for (int mt = 0; mt < MT; mt++)
#pragma unroll
      for (int r = 0; r < 4; r++) {
        float o1 = __shfl_xor(b1[mt][r], off, 64);
        float o2 = __shfl_xor(b2[mt][r], off, 64);
        int oi = __shfl_xor(bi[mt][r], off, 64);
        if (o1 < b1[mt][r] || (o1 == b1[mt][r] && oi < bi[mt][r])) {
          b2[mt][r] = fminf(b1[mt][r], o2);
          b1[mt][r] = o1; bi[mt][r] = oi;
        } else {
          b2[mt][r] = fminf(b2[mt][r], o1);
        }
      }
  }

  // ---- publish per-wave results (uniform in each quad group) ----
  if (m == 0) {  // 4 lanes per wave, one per quad
#pragma unroll
    for (int mt = 0; mt < MT; mt++)
#pragma unroll
      for (int r = 0; r < 4; r++) {
        const int rl = (mt << 4) + (quad << 2) + r;
        sb1[wave][rl] = b1[mt][r];
        sb2[wave][rl] = b2[mt][r];
        sbi[wave][rl] = bi[mt][r];
      }
  }
  __syncthreads();

  // ---- cross-wave merge; wave w finalizes rows [w*16, w*16+16) ----
  const int rl = (wave << 4) + m;  // all 4 quads compute redundantly
  float B1 = sb1[0][rl], B2 = sb2[0][rl];
  int KI = sbi[0][rl];
#pragma unroll
  for (int w2 = 1; w2 < 4; w2++) {
    float o1 = sb1[w2][rl], o2 = sb2[w2][rl];
    int oi = sbi[w2][rl];
    if (o1 < B1) { B2 = fminf(B1, o2); B1 = o1; KI = oi; }
    else B2 = fminf(B2, o1);  // o2 >= o1 so min(B2,o1) suffices
  }
  if (lane < 16) {
    const int row = rowBase + rl;
    out[OUT_IDX_OFF + row] = (float)KI;
    if (B2 - B1 < MARGIN) {
      int slot = atomicAdd(flagCnt, 1);
      flagList[slot] = row;
    }
  }

  // ---- epilogue: wave's 16 rows, 16 lanes x f32x4 per row, 4 rows/iter ----
  float lossAcc = 0.f;
#pragma unroll
  for (int sub = 0; sub < 4; sub++) {
    const int ro = (sub << 2) + quad;                 // row offset 0..15
    const int row = rowBase + (wave << 4) + ro;
    const int kr = __shfl(KI, ro, 64);                // lane ro (quad0,m=ro) has row ro's KI
    f32x4 zv = *(const f32x4*)(z + (size_t)row * DD + (m << 2));
    f32x4 wv = *(const f32x4*)(W + (kr << 6) + (m << 2));
    f32x4 ov;
#pragma unroll
    for (int j = 0; j < 4; j++) {
      float tt = wv[j] - zv[j];
      ov[j] = zv[j] + tt;  // matches reference z + (z_q - z)
      float dl = zv[j] - ov[j];
      lossAcc = fmaf(dl, dl, lossAcc);
    }
    *(f32x4*)(out + (size_t)row * DD + (m << 2)) = ov;
  }

  // ---- block-level loss reduction (1 atomic per block, not per wave) ----
#pragma unroll
  for (int off = 1; off < 64; off <<= 1) lossAcc += __shfl_xor(lossAcc, off, 64);
  if (lane == 0) lw[wave] = lossAcc;
  __syncthreads();
  if (tid == 0) atomicAdd(lossSum, (lw[0] + lw[1]) + (lw[2] + lw[3]));
}

// ---------------------------------------------------------------------------
// Kernel 2: numpy-f32 replication for flagged rows + patch out/loss.
// dist_np = fl32( fl32(A + wnp[k]) - fl32(2*C) ), C = f64 dot rounded once.
// Tail: last-block-done pattern finalizes the loss.
// ---------------------------------------------------------------------------
__global__ void k_refine(const float* __restrict__ z, const float* __restrict__ W,
                         const float* __restrict__ wnp, float* __restrict__ out,
                         const int* __restrict__ flagList,
                         const int* __restrict__ flagCnt,
                         float* __restrict__ lossSum, int* __restrict__ doneCnt) {
  int nflag = *flagCnt;
  int lane = threadIdx.x & 63;
  int wave = (blockIdx.x * blockDim.x + threadIdx.x) >> 6;
  int nWaves = (gridDim.x * blockDim.x) >> 6;

  for (int f = wave; f < nflag; f += nWaves) {
    int row = flagList[f];
    const float* zr = z + (size_t)row * DD;
    float A = np_sumsq64(zr);

    float best = 1e30f;
    int bk = 0x7fffffff;
#pragma unroll
    for (int j = 0; j < KC / 64; j++) {
      int k = lane + (j << 6);
      const float* wk = W + (k << 6);
      double cd = 0.0;
      for (int d = 0; d < DD; d++) cd = fma((double)zr[d], (double)wk[d], cd);
      float twoC = (float)(2.0 * cd);
      float dist;
      {
#pragma clang fp contract(off)
        float t1 = A + wnp[k];
        dist = t1 - twoC;
      }
      if (dist < best || (dist == best && k < bk)) { best = dist; bk = k; }
    }
#pragma unroll
    for (int off = 1; off < 64; off <<= 1) {
      float ov = __shfl_xor(best, off, 64);
      int ok = __shfl_xor(bk, off, 64);
      if (ov < best || (ov == best && ok < bk)) { best = ov; bk = ok; }
    }

    int kold = (int)out[OUT_IDX_OFF + row];
    if (bk != kold) {
      float zv = zr[lane];
      float wN = W[(bk << 6) + lane];
      float oOld = out[(size_t)row * DD + lane];
      float tN = wN - zv;
      float oN = zv + tN;
      out[(size_t)row * DD + lane] = oN;
      float dN = zv - oN, dO = zv - oOld;
      float delta = dN * dN - dO * dO;
#pragma unroll
      for (int off = 1; off < 64; off <<= 1) delta += __shfl_xor(delta, off, 64);
      if (lane == 0) {
        atomicAdd(lossSum, delta);
        out[OUT_IDX_OFF + row] = (float)bk;
      }
    }
  }

  // ---- finalize: last block to arrive writes the loss scalar ----
  __syncthreads();
  if (threadIdx.x == 0) {
    __threadfence();
    int d = atomicAdd(doneCnt, 1);
    if (d == (int)gridDim.x - 1) {
      float s = atomicAdd(lossSum, 0.0f);  // atomic read sees all prior adds
      out[OUT_LOSS_OFF] = 0.25f * s / (float)NELEM;
    }
  }
}

extern "C" void kernel_launch(void* const* d_in, const int* in_sizes, int n_in,
                              void* d_out, int out_size, void* d_ws, size_t ws_size,
                              hipStream_t stream) {
  const float* z = (const float*)d_in[0];
  const float* W = (const float*)d_in[1];
  float* out = (float*)d_out;
  char* ws = (char*)d_ws;

  int* flagCnt = (int*)(ws + WSO_CNT);
  int* doneCnt = (int*)(ws + WSO_DONE);
  float* lossSum = (float*)(ws + WSO_LOSS);
  float* wnorm = (float*)(ws + WSO_WNORM);
  short8* Bh = (short8*)(ws + WSO_BH);
  short8* Bl = (short8*)(ws + WSO_BL);
  int* flagList = (int*)(ws + WSO_LIST);

  k_prep<<<16, 256, 0, stream>>>(W, Bh, Bl, wnorm, flagCnt, doneCnt, lossSum);
  k_screen<<<NROWS / ROWS_PER_BLOCK, 256, 0, stream>>>(z, W, Bh, Bl, wnorm, out,
                                                       flagList, flagCnt, lossSum);
  k_refine<<<256, 256, 0, stream>>>(z, W, wnorm, out, flagList, flagCnt,
                                    lossSum, doneCnt);
}

// Round 4
// 203.243 us; speedup vs baseline: 2.4190x; 1.1624x over previous
//
#include <hip/hip_runtime.h>
#include <hip/hip_bf16.h>
#include <math.h>

#define NROWS 131072   // B*T = 32*4096
#define KC    512      // codebook size
#define DD    64       // embedding dim
#define NELEM (NROWS * DD)

#define OUT_IDX_OFF  NELEM
#define OUT_LOSS_OFF (NELEM + NROWS)

#define MARGIN 3e-5f

// d_ws byte offsets
#define WSO_CNT   0                        // int   flagged-row count
#define WSO_DONE  4                        // int   refine blocks-done count
#define WSO_LOSS  8                        // float loss accumulator
#define WSO_WNORM 64                       // float wnorm_np[512]
#define WSO_BH    4096                     // bf16 frags W-hi: 32 tiles x 2 kh x 64 lanes x 8 = 64 KB
#define WSO_BL    (WSO_BH + 65536)         // bf16 frags W-lo: 64 KB
#define WSO_LIST  (WSO_BL + 65536)         // int flagList[NROWS]

typedef __attribute__((ext_vector_type(8))) short short8;
typedef __attribute__((ext_vector_type(4))) float f32x4;

// ---------------------------------------------------------------------------
// bf16 helpers (RNE via __float2bfloat16)
// ---------------------------------------------------------------------------
__device__ __forceinline__ short f2bf_bits(float f) {
  __hip_bfloat16 h = __float2bfloat16(f);
  short s; __builtin_memcpy(&s, &h, 2); return s;
}
__device__ __forceinline__ float bfbits2f(short s) {
  __hip_bfloat16 h; __builtin_memcpy(&h, &s, 2);
  return __bfloat162float(h);
}
// split 8 consecutive f32 into bf16 hi + bf16 lo(residual)
__device__ __forceinline__ void cvt8(const float* __restrict__ p, short8& hi, short8& lo) {
#pragma unroll
  for (int j = 0; j < 8; j++) {
    float f = p[j];
    short hb = f2bf_bits(f);
    float r = f - bfbits2f(hb);
    hi[j] = hb;
    lo[j] = f2bf_bits(r);
  }
}

// ---------------------------------------------------------------------------
// numpy's pairwise sum of squares for 64 contiguous f32 (8-accumulator tree).
// contract(off) REQUIRED (hipcc default -ffp-contract=fast would fuse).
// ---------------------------------------------------------------------------
__device__ __forceinline__ float np_sumsq64(const float* __restrict__ p) {
#pragma clang fp contract(off)
  float r0 = p[0] * p[0], r1 = p[1] * p[1], r2 = p[2] * p[2], r3 = p[3] * p[3];
  float r4 = p[4] * p[4], r5 = p[5] * p[5], r6 = p[6] * p[6], r7 = p[7] * p[7];
  for (int i = 8; i < 64; i += 8) {
    r0 = r0 + p[i + 0] * p[i + 0];
    r1 = r1 + p[i + 1] * p[i + 1];
    r2 = r2 + p[i + 2] * p[i + 2];
    r3 = r3 + p[i + 3] * p[i + 3];
    r4 = r4 + p[i + 4] * p[i + 4];
    r5 = r5 + p[i + 5] * p[i + 5];
    r6 = r6 + p[i + 6] * p[i + 6];
    r7 = r7 + p[i + 7] * p[i + 7];
  }
  return ((r0 + r1) + (r2 + r3)) + ((r4 + r5) + (r6 + r7));
}

// ---------------------------------------------------------------------------
// Kernel 0: prep. (a) W -> MFMA-B-fragment-major bf16 hi/lo arrays.
// B[k=d][n=cw] fragment for 16x16x32: lane L holds B[(L>>4)*8+j][L&15], j=0..7.
// Element (tile t, khalf h, lane L, j) = W[cw = t*16+(L&15)][d = 32h+(L>>4)*8+j].
// (b) wnorm_np[k] = numpy-exact sum(W[k]^2).  (c) zero ws scalars.
// ---------------------------------------------------------------------------
__global__ void k_prep(const float* __restrict__ W, short8* __restrict__ Bh,
                       short8* __restrict__ Bl, float* __restrict__ wnorm,
                       int* __restrict__ flagCnt, int* __restrict__ doneCnt,
                       float* __restrict__ lossSum) {
  int gtid = blockIdx.x * blockDim.x + threadIdx.x;  // 0..4095
  if (gtid == 0) { *flagCnt = 0; *doneCnt = 0; *lossSum = 0.0f; }
  int t = gtid >> 7, rem = gtid & 127;
  int h = rem >> 6, L = rem & 63;
  int cw = (t << 4) + (L & 15);
  int dbase = (h << 5) + ((L >> 4) << 3);
  short8 hi, lo;
  cvt8(W + (cw << 6) + dbase, hi, lo);
  Bh[gtid] = hi;  // gtid == ((t*2+h)*64 + L)
  Bl[gtid] = lo;
  if (gtid < KC) wnorm[gtid] = np_sumsq64(W + (gtid << 6));
}

// ---------------------------------------------------------------------------
// Kernel 0b: z -> MFMA-A-fragment bf16 hi/lo arrays, STAGED IN `out`.
// A-frag for 16x16x32: lane L holds A[row=L&15][k=(L>>4)*8+j].
// RowTile r16's 4 frags (2 khalves x {hi,lo}) occupy exactly bytes
// [r16*4096, r16*4096+4096) of out — the same bytes rows r16*16..+16 of
// z_q_st will occupy. Each screen-wave reads only its own rows' frags
// before writing those rows -> no hazard, no extra workspace.
// Frag index F(r16,h,p) = ((r16*2+h)*2+p), short8 element [F*64 + L].
// ---------------------------------------------------------------------------
__global__ void k_prep_z(const float* __restrict__ z, short8* __restrict__ Af) {
  int gtid = blockIdx.x * blockDim.x + threadIdx.x;  // 0 .. 1048575
  int r16 = gtid >> 7, rem = gtid & 127;
  int h = rem >> 6, L = rem & 63;
  const float* zp = z + ((size_t)((r16 << 4) + (L & 15)) << 6) + (h << 5) + ((L >> 4) << 3);
  short8 hi, lo;
  cvt8(zp, hi, lo);
  size_t F = ((size_t)(r16 << 1) + h) << 1;
  Af[F * 64 + L] = hi;
  Af[(F + 1) * 64 + L] = lo;
}

// ---------------------------------------------------------------------------
// Kernel 1: fused MFMA screen + argmin + epilogue.
// ROUND-4 STRUCTURE (post-mortem of r0/r1/r3: all ~80% latency-stalled;
// occupancy moves didn't help because per-wave overhead scaled with waves):
//   - A-frags PRECOMPUTED (k_prep_z) -> wave start = 8 coalesced 16B loads,
//     no cvt8 VALU burst, no cold z-load burst.
//   - B codebook in LDS: staged per block in two 64KB phases (static
//     __shared__). Main-loop B access = ds_read_b128 at lane*16 (the
//     canonical conflict-free pattern) instead of L2 loads w/ 1-deep pipe.
//   - 8 waves x 32 rows (MT=2), grid 512, launch_bounds(512,4):
//     LDS 64KB -> 2 blocks/CU -> 16 waves/CU = 4/SIMD; VGPR ~110 <= 128 cap
//     (r2's spill disaster was cap 40 vs footprint 150; here margin ~20).
//     MT=2's r1 penalties void: B is in LDS (no per-wave global B stream),
//     TLP 4/SIMD covers the halved MFMA ILP.
//   - No cross-wave merge: each wave owns its 32 rows end-to-end.
// Numerics bit-identical to r0: same cvt8 frags, same MFMA accumulation
// order, same score/margin/tie-break logic.
// ---------------------------------------------------------------------------
#define MT 2
#define ROWS_PER_WAVE 32
#define ROWS_PER_BLOCK 256   // 8 waves
#define SCREEN_THREADS 512

__global__ __launch_bounds__(SCREEN_THREADS, 4) void k_screen(
    const float* __restrict__ z, const float* __restrict__ W,
    const short8* __restrict__ Bh, const short8* __restrict__ Bl,
    const float* __restrict__ wnorm, float* out,  // out: frags in, results out (aliased; no restrict)
    int* __restrict__ flagList, int* __restrict__ flagCnt,
    float* __restrict__ lossSum) {
  const int tid = threadIdx.x;
  const int lane = tid & 63;
  const int wave = tid >> 6;
  const int m = lane & 15, quad = lane >> 4;
  const int rowBase = blockIdx.x * ROWS_PER_BLOCK + wave * ROWS_PER_WAVE;
  const int r16base = rowBase >> 4;

  __shared__ short8 sB[4096];  // 64 KB: [hi: frag(tl,h)*64+L | lo at +2048]

  // ---- A fragments: precomputed, 8 coalesced 16B loads ----
  const short8* Af = (const short8*)out;
  short8 Ah[MT][2], Al[MT][2];
#pragma unroll
  for (int mt = 0; mt < MT; mt++)
#pragma unroll
    for (int h = 0; h < 2; h++) {
      const size_t F = ((size_t)((r16base + mt) << 1) + h) << 1;
      Ah[mt][h] = Af[F * 64 + lane];
      Al[mt][h] = Af[(F + 1) * 64 + lane];
    }

  float b1[MT][4], b2[MT][4];
  int bi[MT][4];
#pragma unroll
  for (int mt = 0; mt < MT; mt++)
#pragma unroll
    for (int r = 0; r < 4; r++) { b1[mt][r] = 1e30f; b2[mt][r] = 1e30f; bi[mt][r] = 0; }

  // ---- two phases of 16 codeword tiles, B staged in LDS ----
  for (int ph = 0; ph < 2; ph++) {
    if (ph) __syncthreads();  // all waves done reading phase-0 LDS
#pragma unroll
    for (int c = 0; c < 4; c++) {
      const int i = (c << 9) + tid;          // 0..2047, lanes contiguous
      sB[i] = Bh[(ph << 11) + i];
      sB[2048 + i] = Bl[(ph << 11) + i];
    }
    __syncthreads();

#pragma unroll 2
    for (int tl = 0; tl < 16; tl++) {
      const int t = (ph << 4) + tl;
      short8 Bhf[2], Blf[2];
#pragma unroll
      for (int h = 0; h < 2; h++) {
        Bhf[h] = sB[(((tl << 1) + h) << 6) + lane];
        Blf[h] = sB[2048 + (((tl << 1) + h) << 6) + lane];
      }
      const float wn = wnorm[(t << 4) + m];

      f32x4 acc[MT] = {{0.f, 0.f, 0.f, 0.f}, {0.f, 0.f, 0.f, 0.f}};
#pragma unroll
      for (int h = 0; h < 2; h++) {
#pragma unroll
        for (int mt = 0; mt < MT; mt++)
          acc[mt] = __builtin_amdgcn_mfma_f32_16x16x32_bf16(Ah[mt][h], Bhf[h], acc[mt], 0, 0, 0);
#pragma unroll
        for (int mt = 0; mt < MT; mt++)
          acc[mt] = __builtin_amdgcn_mfma_f32_16x16x32_bf16(Al[mt][h], Bhf[h], acc[mt], 0, 0, 0);
#pragma unroll
        for (int mt = 0; mt < MT; mt++)
          acc[mt] = __builtin_amdgcn_mfma_f32_16x16x32_bf16(Ah[mt][h], Blf[h], acc[mt], 0, 0, 0);
      }

      const int colv = (t << 4) + m;
#pragma unroll
      for (int mt = 0; mt < MT; mt++)
#pragma unroll
        for (int r = 0; r < 4; r++) {
          float s = fmaf(-2.0f, acc[mt][r], wn);
          if (s < b1[mt][r]) { b2[mt][r] = b1[mt][r]; b1[mt][r] = s; bi[mt][r] = colv; }
          else b2[mt][r] = fminf(b2[mt][r], s);
        }
    }
  }

  // ---- in-wave butterfly over the 16 col-lanes (within quad group) ----
#pragma unroll
  for (int off = 1; off < 16; off <<= 1) {
#pragma unroll
    for (int mt = 0; mt < MT; mt++)
#pragma unroll
      for (int r = 0; r < 4; r++) {
        float o1 = __shfl_xor(b1[mt][r], off, 64);
        float o2 = __shfl_xor(b2[mt][r], off, 64);
        int oi = __shfl_xor(bi[mt][r], off, 64);
        if (o1 < b1[mt][r] || (o1 == b1[mt][r] && oi < bi[mt][r])) {
          b2[mt][r] = fminf(b1[mt][r], o2);
          b1[mt][r] = o1; bi[mt][r] = oi;
        } else {
          b2[mt][r] = fminf(b2[mt][r], o1);
        }
      }
  }

  // ---- epilogue: quad-parallel, shfl-free. Quad q owns rows mt*16+q*4+r;
  // its 16 lanes cover the 64 cols as f32x4. (b1,b2,bi) quad-uniform. ----
  float lossAcc = 0.f;
#pragma unroll
  for (int mt = 0; mt < MT; mt++)
#pragma unroll
    for (int r = 0; r < 4; r++) {
      const int row = rowBase + (mt << 4) + (quad << 2) + r;
      const int ki = bi[mt][r];
      f32x4 zv = *(const f32x4*)(z + (size_t)row * DD + (m << 2));
      f32x4 wv = *(const f32x4*)(W + (ki << 6) + (m << 2));
      f32x4 ov;
#pragma unroll
      for (int j = 0; j < 4; j++) {
        float tt = wv[j] - zv[j];
        ov[j] = zv[j] + tt;  // matches reference z + (z_q - z)
        float dl = zv[j] - ov[j];
        lossAcc = fmaf(dl, dl, lossAcc);
      }
      *(f32x4*)(out + (size_t)row * DD + (m << 2)) = ov;
      if (m == 0) {
        out[OUT_IDX_OFF + row] = (float)ki;
        if (b2[mt][r] - b1[mt][r] < MARGIN) {
          int slot = atomicAdd(flagCnt, 1);
          flagList[slot] = row;
        }
      }
    }

#pragma unroll
  for (int off = 1; off < 64; off <<= 1) lossAcc += __shfl_xor(lossAcc, off, 64);
  if (lane == 0) atomicAdd(lossSum, lossAcc);
}

// ---------------------------------------------------------------------------
// Kernel 2: numpy-f32 replication for flagged rows + patch out/loss.
// dist_np = fl32( fl32(A + wnp[k]) - fl32(2*C) ), C = f64 dot rounded once.
// Tail: last-block-done pattern finalizes the loss.
// ---------------------------------------------------------------------------
__global__ void k_refine(const float* __restrict__ z, const float* __restrict__ W,
                         const float* __restrict__ wnp, float* __restrict__ out,
                         const int* __restrict__ flagList,
                         const int* __restrict__ flagCnt,
                         float* __restrict__ lossSum, int* __restrict__ doneCnt) {
  int nflag = *flagCnt;
  int lane = threadIdx.x & 63;
  int wave = (blockIdx.x * blockDim.x + threadIdx.x) >> 6;
  int nWaves = (gridDim.x * blockDim.x) >> 6;

  for (int f = wave; f < nflag; f += nWaves) {
    int row = flagList[f];
    const float* zr = z + (size_t)row * DD;
    float A = np_sumsq64(zr);

    float best = 1e30f;
    int bk = 0x7fffffff;
#pragma unroll
    for (int j = 0; j < KC / 64; j++) {
      int k = lane + (j << 6);
      const float* wk = W + (k << 6);
      double cd = 0.0;
      for (int d = 0; d < DD; d++) cd = fma((double)zr[d], (double)wk[d], cd);
      float twoC = (float)(2.0 * cd);
      float dist;
      {
#pragma clang fp contract(off)
        float t1 = A + wnp[k];
        dist = t1 - twoC;
      }
      if (dist < best || (dist == best && k < bk)) { best = dist; bk = k; }
    }
#pragma unroll
    for (int off = 1; off < 64; off <<= 1) {
      float ov = __shfl_xor(best, off, 64);
      int ok = __shfl_xor(bk, off, 64);
      if (ov < best || (ov == best && ok < bk)) { best = ov; bk = ok; }
    }

    int kold = (int)out[OUT_IDX_OFF + row];
    if (bk != kold) {
      float zv = zr[lane];
      float wN = W[(bk << 6) + lane];
      float oOld = out[(size_t)row * DD + lane];
      float tN = wN - zv;
      float oN = zv + tN;
      out[(size_t)row * DD + lane] = oN;
      float dN = zv - oN, dO = zv - oOld;
      float delta = dN * dN - dO * dO;
#pragma unroll
      for (int off = 1; off < 64; off <<= 1) delta += __shfl_xor(delta, off, 64);
      if (lane == 0) {
        atomicAdd(lossSum, delta);
        out[OUT_IDX_OFF + row] = (float)bk;
      }
    }
  }

  // ---- finalize: last block to arrive writes the loss scalar ----
  __syncthreads();
  if (threadIdx.x == 0) {
    __threadfence();
    int d = atomicAdd(doneCnt, 1);
    if (d == (int)gridDim.x - 1) {
      float s = atomicAdd(lossSum, 0.0f);  // atomic read sees all prior adds
      out[OUT_LOSS_OFF] = 0.25f * s / (float)NELEM;
    }
  }
}

extern "C" void kernel_launch(void* const* d_in, const int* in_sizes, int n_in,
                              void* d_out, int out_size, void* d_ws, size_t ws_size,
                              hipStream_t stream) {
  const float* z = (const float*)d_in[0];
  const float* W = (const float*)d_in[1];
  float* out = (float*)d_out;
  char* ws = (char*)d_ws;

  int* flagCnt = (int*)(ws + WSO_CNT);
  int* doneCnt = (int*)(ws + WSO_DONE);
  float* lossSum = (float*)(ws + WSO_LOSS);
  float* wnorm = (float*)(ws + WSO_WNORM);
  short8* Bh = (short8*)(ws + WSO_BH);
  short8* Bl = (short8*)(ws + WSO_BL);
  int* flagList = (int*)(ws + WSO_LIST);

  k_prep<<<16, 256, 0, stream>>>(W, Bh, Bl, wnorm, flagCnt, doneCnt, lossSum);
  k_prep_z<<<4096, 256, 0, stream>>>(z, (short8*)out);
  k_screen<<<NROWS / ROWS_PER_BLOCK, SCREEN_THREADS, 0, stream>>>(
      z, W, Bh, Bl, wnorm, out, flagList, flagCnt, lossSum);
  k_refine<<<256, 256, 0, stream>>>(z, W, wnorm, out, flagList, flagCnt,
                                    lossSum, doneCnt);
}